// Round 2
// baseline (74.186 us; speedup 1.0000x reference)
//
#include <hip/hip_runtime.h>
#include <hip/hip_bf16.h>

// Sliding-window causal attention, B=4, S=4096, d=64, window [i-256, i].
// Round 5: occupancy attack. 32-query blocks -> 512 blocks = 2 blocks/CU
// (4 waves/SIMD, 2x round-4's latency hiding).
//  - 8 waves: 2 query-stripes x 4 key-groups (32 keys each per 128-key iter).
//  - K/V staged in 128-key iterations: 2 full + 1 diagonal (32 keys + zero pad).
//    Single LDS buffer; register prefetch (8 float4/thread) is the double buffer.
//  - LDS 76.4 KB (<80) -> 2 blocks/CU; __launch_bounds__(512,4) caps VGPR at 128.
//  - XCD-bijective block swizzle: each XCD owns contiguous q-ranges -> window
//    re-reads hit its private L2 (~2.4 MB working set < 4 MB).
// Layouts (HW-verified per guide §3): A[m=lane&15][k=quad*8+j];
// C/D col=lane&15, row=quad*4+reg.

#define LOG2E 1.4426950408889634f

typedef __attribute__((ext_vector_type(8))) short  frag;    // 8 bf16
typedef __attribute__((ext_vector_type(4))) float  f32x4;   // C/D

static __device__ inline short f2bf(float x) {
    __hip_bfloat16 h = __float2bfloat16(x);   // RTNE
    return __builtin_bit_cast(short, h);
}

#define DPPF(x, ctrl) __builtin_bit_cast(float, \
    __builtin_amdgcn_mov_dpp(__builtin_bit_cast(int, (x)), (ctrl), 0xF, 0xF, true))

static __device__ inline float red16_max(float x) {
    x = fmaxf(x, DPPF(x, 0xB1));   // quad_perm xor 1
    x = fmaxf(x, DPPF(x, 0x4E));   // quad_perm xor 2
    x = fmaxf(x, DPPF(x, 0x141));  // row_half_mirror (~xor 4)
    x = fmaxf(x, DPPF(x, 0x140));  // row_mirror      (~xor 8)
    return x;
}
static __device__ inline float red16_sum(float x) {
    x += DPPF(x, 0xB1);
    x += DPPF(x, 0x4E);
    x += DPPF(x, 0x141);
    x += DPPF(x, 0x140);
    return x;
}

#define KSTR 72    // Q/K LDS row stride (bf16)
#define VSTR 136   // Vt row stride (bf16): 128 keys + 8 pad
#define PSTR 40    // P tile row stride (16 x 32 keys + pad)
#define OSTR 65    // merge buffer row stride (fp32)

__global__ __launch_bounds__(512, 4) void swa_mfma5(const float* __restrict__ qkv,
                                                    float* __restrict__ out)
{
    __shared__ short Qs[32 * KSTR];          //  4608 B
    __shared__ short Ks[128 * KSTR];         // 18432 B  (one 128-key iter)
    __shared__ short Vt[64 * VSTR];          // 17408 B  Vt[dim][key]
    __shared__ short Pw[8][16 * PSTR];       // 10240 B  per-wave P
    __shared__ float Om[2][3][16 * OSTR];    // 24960 B  groups 1-3 partials
    __shared__ float2 mlbuf[2][3][16];       //   768 B
    // total 76416 B -> 2 blocks/CU (152.8 KB < 160 KB)

    const int b   = blockIdx.y;
    const int xb  = blockIdx.x;
    // bijective XCD swizzle: 128 = 8 XCDs x 16 contiguous q-blocks
    const int qb  = 16 * (xb & 7) + (xb >> 3);
    const int q0  = qb * 32;

    const int t    = threadIdx.x;
    const int w    = t >> 6;         // 0..7
    const int s    = w & 1;          // query stripe: rows 16s..16s+15
    const int g    = w >> 1;         // key group: keys 32g..32g+31 per iter
    const int lane = t & 63;
    const int cl   = lane & 15;
    const int quad = lane >> 4;
    const int ql   = 4 * quad;

    const float4* qkv4 = (const float4*)qkv;   // 48 float4 per (b,seq) row

    // staging coords
    const int r2 = t >> 2;          // 0..127  K/V row within iter
    const int c4 = t & 3;           // float4 col group (4 cols: c4+4i)
    const int rq = t >> 4;          // 0..31   Q row
    const int cq = t & 15;          // Q float4 col

    // iteration validity / left clamps (block-uniform)
    const int lo0 = 256 - q0;                              // it0 invalid-key count
    const int lo1 = (128 - q0 > 0) ? (128 - q0) : 0;       // it1 invalid-key count
    const int it_first = (q0 > 128) ? 0 : ((q0 > 0) ? 1 : 2);

    // ---- stage Q (x 1/8 scale folded in) ----
    {
        const size_t base = (size_t)(b * 4096 + q0 + rq) * 48;
        float4 v = qkv4[base + cq];
        short4 s4 = { f2bf(v.x * 0.125f), f2bf(v.y * 0.125f),
                      f2bf(v.z * 0.125f), f2bf(v.w * 0.125f) };
        *(short4*)&Qs[rq * KSTR + 4 * cq] = s4;
    }

    float4 pK[4], pV[4];
    auto prefetch = [&](int itx) {
        bool valid;
        size_t base;
        if (itx == 2) {                    // diagonal iter: 32 real keys
            valid = (r2 < 32);
            base = (size_t)(b * 4096 + q0 + (r2 & 31)) * 48;
        } else {
            valid = true;
            int rg = q0 - 256 + 128 * itx + r2;
            rg = rg < 0 ? 0 : rg;          // clamp; masked in QK anyway
            base = (size_t)(b * 4096 + rg) * 48;
        }
        #pragma unroll
        for (int i = 0; i < 4; ++i) {
            if (valid) {
                pK[i] = qkv4[base + 16 + c4 + 4 * i];
                pV[i] = qkv4[base + 32 + c4 + 4 * i];
            } else {
                pK[i] = make_float4(0.f, 0.f, 0.f, 0.f);
                pV[i] = make_float4(0.f, 0.f, 0.f, 0.f);
            }
        }
    };

    prefetch(it_first);

    float m[4], l[4];
    f32x4 oacc[4];
    #pragma unroll
    for (int r = 0; r < 4; ++r) { m[r] = -1e30f; l[r] = 0.f; }
    #pragma unroll
    for (int n4 = 0; n4 < 4; ++n4) oacc[n4] = (f32x4){0.f, 0.f, 0.f, 0.f};

    #pragma unroll
    for (int it = 0; it < 3; ++it) {
        if (it < it_first) continue;       // block-uniform

        __syncthreads();   // A: prev iter's readers done (+ Qs visible, 1st iter)

        // ---- cvt + store K (row-major) and V (transposed) ----
        #pragma unroll
        for (int i = 0; i < 4; ++i) {
            short4 k4 = { f2bf(pK[i].x), f2bf(pK[i].y),
                          f2bf(pK[i].z), f2bf(pK[i].w) };
            *(short4*)&Ks[r2 * KSTR + 4 * (c4 + 4 * i)] = k4;
            const int d0 = 4 * (c4 + 4 * i);
            Vt[(d0 + 0) * VSTR + r2] = f2bf(pV[i].x);
            Vt[(d0 + 1) * VSTR + r2] = f2bf(pV[i].y);
            Vt[(d0 + 2) * VSTR + r2] = f2bf(pV[i].z);
            Vt[(d0 + 3) * VSTR + r2] = f2bf(pV[i].w);
        }
        __syncthreads();   // B: tiles visible

        if (it < 2) prefetch(it + 1);      // lands during compute

        const frag qf0 = *(const frag*)&Qs[(16 * s + cl) * KSTR + 8 * quad];
        const frag qf1 = *(const frag*)&Qs[(16 * s + cl) * KSTR + 32 + 8 * quad];

        // ---- S = Q K^T over this group's 2 key-tiles ----
        f32x4 sc[2];
        #pragma unroll
        for (int u = 0; u < 2; ++u) {
            const int krow = 32 * g + 16 * u;
            sc[u] = (f32x4){0.f, 0.f, 0.f, 0.f};
            const frag kf0 = *(const frag*)&Ks[(krow + cl) * KSTR + 8 * quad];
            const frag kf1 = *(const frag*)&Ks[(krow + cl) * KSTR + 32 + 8 * quad];
            sc[u] = __builtin_amdgcn_mfma_f32_16x16x32_bf16(qf0, kf0, sc[u], 0, 0, 0);
            sc[u] = __builtin_amdgcn_mfma_f32_16x16x32_bf16(qf1, kf1, sc[u], 0, 0, 0);
        }

        // ---- masks ----
        if (it == 0) {           // window-left per-row + negative-key clamp
            #pragma unroll
            for (int u = 0; u < 2; ++u) {
                const int o = 32 * g + 16 * u + cl;
                #pragma unroll
                for (int r = 0; r < 4; ++r) {
                    const int rb = 16 * s + ql + r;
                    if (o < rb || o < lo0) sc[u][r] = -1e30f;
                }
            }
        } else if (it == 1) {    // negative-key clamp only (uniform)
            if (lo1 > 0) {
                #pragma unroll
                for (int u = 0; u < 2; ++u) {
                    const int o = 32 * g + 16 * u + cl;
                    #pragma unroll
                    for (int r = 0; r < 4; ++r)
                        if (o < lo1) sc[u][r] = -1e30f;
                }
            }
        } else {                 // diagonal: causal (also masks zero-pad keys)
            #pragma unroll
            for (int u = 0; u < 2; ++u) {
                const int o = 32 * g + 16 * u + cl;
                #pragma unroll
                for (int r = 0; r < 4; ++r) {
                    const int rb = 16 * s + ql + r;
                    if (o > rb) sc[u][r] = -1e30f;
                }
            }
        }

        // ---- online softmax (DPP 16-lane reductions) ----
        #pragma unroll
        for (int r = 0; r < 4; ++r) {
            float mx = red16_max(fmaxf(sc[0][r], sc[1][r]));
            const float mnew  = fmaxf(m[r], mx);
            const float alpha = __builtin_amdgcn_exp2f((m[r] - mnew) * LOG2E);
            m[r] = mnew;
            float sum = 0.f;
            #pragma unroll
            for (int u = 0; u < 2; ++u) {
                float p = (sc[u][r] <= -1e29f)
                            ? 0.f
                            : __builtin_amdgcn_exp2f((sc[u][r] - mnew) * LOG2E);
                Pw[w][(ql + r) * PSTR + 16 * u + cl] = f2bf(p);
                sum += p;
            }
            l[r] = l[r] * alpha + red16_sum(sum);
            #pragma unroll
            for (int n4 = 0; n4 < 4; ++n4) oacc[n4][r] *= alpha;
        }

        // ---- O += P V  (P wave-private: lgkmcnt only, no barrier) ----
        const frag pf = *(const frag*)&Pw[w][cl * PSTR + 8 * quad];
        #pragma unroll
        for (int n4 = 0; n4 < 4; ++n4) {
            const frag vf = *(const frag*)&Vt[(16 * n4 + cl) * VSTR + 32 * g + 8 * quad];
            oacc[n4] = __builtin_amdgcn_mfma_f32_16x16x32_bf16(pf, vf, oacc[n4], 0, 0, 0);
        }
    }

    // ---- merge the four key-groups per stripe ----
    if (g != 0) {
        #pragma unroll
        for (int n4 = 0; n4 < 4; ++n4)
            #pragma unroll
            for (int r = 0; r < 4; ++r)
                Om[s][g - 1][(ql + r) * OSTR + 16 * n4 + cl] = oacc[n4][r];
        if (cl == 0)
            #pragma unroll
            for (int r = 0; r < 4; ++r)
                mlbuf[s][g - 1][ql + r] = make_float2(m[r], l[r]);
    }
    __syncthreads();
    if (g == 0) {
        #pragma unroll
        for (int r = 0; r < 4; ++r) {
            float M = m[r];
            float L = l[r];
            float acc[4];
            #pragma unroll
            for (int n4 = 0; n4 < 4; ++n4) acc[n4] = oacc[n4][r];
            #pragma unroll
            for (int p = 0; p < 3; ++p) {
                const float2 ml = mlbuf[s][p][ql + r];
                const float Mn = fmaxf(M, ml.x);
                const float a0 = __builtin_amdgcn_exp2f((M    - Mn) * LOG2E);
                const float a1 = __builtin_amdgcn_exp2f((ml.x - Mn) * LOG2E);
                L = L * a0 + ml.y * a1;
                #pragma unroll
                for (int n4 = 0; n4 < 4; ++n4)
                    acc[n4] = acc[n4] * a0
                            + Om[s][p][(ql + r) * OSTR + 16 * n4 + cl] * a1;
                M = Mn;
            }
            const float inv = 1.0f / L;
            const size_t row = (size_t)(b * 4096 + q0 + 16 * s + ql + r) * 64;
            #pragma unroll
            for (int n4 = 0; n4 < 4; ++n4)
                out[row + 16 * n4 + cl] = acc[n4] * inv;
        }
    }
}

extern "C" void kernel_launch(void* const* d_in, const int* in_sizes, int n_in,
                              void* d_out, int out_size, void* d_ws, size_t ws_size,
                              hipStream_t stream) {
    const float* qkv = (const float*)d_in[0];
    float* out = (float*)d_out;
    dim3 grid(128, 4);
    dim3 block(512);
    hipLaunchKernelGGL(swa_mfma5, grid, block, 0, stream, qkv, out);
}

// Round 3
// 70.808 us; speedup vs baseline: 1.0477x; 1.0477x over previous
//
#include <hip/hip_runtime.h>
#include <hip/hip_bf16.h>

// Sliding-window causal attention, B=4, S=4096, d=64, window [i-256, i].
// Round 6: same 64-query blocks as the 67.3 µs best (same staging traffic),
// but 1024 threads = 16 waves -> 4 waves/SIMD (2x latency hiding):
//  - 4 q-stripes x 4 key-groups of 16 keys; per-thread softmax halved.
//  - PV keeps the HW-verified 16x16x32 path: fragment halves for keys 16..31
//    are register zeros (quads 2-3 skip the LDS read), so no layout risk and
//    no extra LDS read traffic.
//  - V-transpose staging stores: VSTR=65 -> 4*65*c16 spreads the 4 scalar
//    stores across all 32 banks (2-way = free) vs 8-way conflict before.
//  - Merge = round-5-verified 3-partial merge, 4 stripes.
// LDS 86.5 KB, 1 block/CU, launch_bounds(1024,4) caps VGPR at 128 (live ~90).
// Layouts (HW-verified per guide §3): A[m=lane&15][k=quad*8+j];
// C/D col=lane&15, row=quad*4+reg.

#define LOG2E 1.4426950408889634f

typedef __attribute__((ext_vector_type(8))) short  frag;    // 8 bf16
typedef __attribute__((ext_vector_type(4))) float  f32x4;   // C/D

static __device__ inline short f2bf(float x) {
    __hip_bfloat16 h = __float2bfloat16(x);   // RTNE
    return __builtin_bit_cast(short, h);
}

#define DPPF(x, ctrl) __builtin_bit_cast(float, \
    __builtin_amdgcn_mov_dpp(__builtin_bit_cast(int, (x)), (ctrl), 0xF, 0xF, true))

static __device__ inline float red16_max(float x) {
    x = fmaxf(x, DPPF(x, 0xB1));   // quad_perm xor 1
    x = fmaxf(x, DPPF(x, 0x4E));   // quad_perm xor 2
    x = fmaxf(x, DPPF(x, 0x141));  // row_half_mirror (~xor 4)
    x = fmaxf(x, DPPF(x, 0x140));  // row_mirror      (~xor 8)
    return x;
}
static __device__ inline float red16_sum(float x) {
    x += DPPF(x, 0xB1);
    x += DPPF(x, 0x4E);
    x += DPPF(x, 0x141);
    x += DPPF(x, 0x140);
    return x;
}

#define KSTR 72    // Q/K LDS row stride (bf16)
#define VSTR 65    // Vt row stride: 4*VSTR*c16 covers 32 banks (2-way free)
#define PSTR 20    // P tile row stride (16 keys + pad)
#define OSTR 65    // merge buffer row stride (fp32)

__global__ __launch_bounds__(1024, 4) void swa_mfma6(const float* __restrict__ qkv,
                                                     float* __restrict__ out)
{
    __shared__ short Qs[64 * KSTR];          //  9216 B
    __shared__ short Ks[64 * KSTR];          //  9216 B (one 64-key chunk)
    __shared__ short Vt[64 * VSTR + 16];     //  8352 B  Vt[dim][key]
    __shared__ short Pw[16][16 * PSTR];      // 10240 B  per-wave P (16q x 16k)
    __shared__ float Om[4][3][16 * OSTR];    // 49920 B  groups 1-3 partials
    __shared__ float2 mlbuf[4][3][16];       //  1536 B
    // total 88.5 KB -> one 16-wave block per CU = 4 waves/SIMD

    const int b    = blockIdx.y;
    const int q0   = blockIdx.x * 64;
    const int t    = threadIdx.x;
    const int w    = t >> 6;        // 0..15
    const int s    = w & 3;         // query stripe: rows 16s..16s+15
    const int g    = w >> 2;        // key group: keys 16g..16g+15 per chunk
    const int lane = t & 63;
    const int cl   = lane & 15;
    const int quad = lane >> 4;
    const int ql   = 4 * quad;

    const float4* qkv4 = (const float4*)qkv;   // 48 float4 per (b,seq) row
    const int r_st = t >> 4;        // staging row 0..63
    const int c16  = t & 15;        // staging float4-col

    const int c0 = (q0 >= 256) ? 0 : (4 - (q0 >> 6));

    // ---- stage Q (x 1/8 scale folded in); 1 float4/thread ----
    {
        const size_t base = (size_t)(b * 4096 + q0 + r_st) * 48;
        float4 v = qkv4[base + c16];
        short4 s4 = { f2bf(v.x * 0.125f), f2bf(v.y * 0.125f),
                      f2bf(v.z * 0.125f), f2bf(v.w * 0.125f) };
        *(short4*)&Qs[r_st * KSTR + 4 * c16] = s4;
    }

    // ---- prefetch chunk c0 (1 K + 1 V float4 per thread) ----
    float4 pK, pV;
    {
        const int kb = q0 - 256 + 64 * c0;
        const size_t base = (size_t)(b * 4096 + kb + r_st) * 48;
        pK = qkv4[base + 16 + c16];
        pV = qkv4[base + 32 + c16];
    }

    __syncthreads();   // Qs visible
    const frag qf0 = *(const frag*)&Qs[(16 * s + cl) * KSTR + 8 * quad];
    const frag qf1 = *(const frag*)&Qs[(16 * s + cl) * KSTR + 32 + 8 * quad];

    float m[4], l[4];
    f32x4 oacc[4];
    #pragma unroll
    for (int r = 0; r < 4; ++r) { m[r] = -1e30f; l[r] = 0.f; }
    #pragma unroll
    for (int n4 = 0; n4 < 4; ++n4) oacc[n4] = (f32x4){0.f, 0.f, 0.f, 0.f};

    for (int c = c0; c < 5; ++c) {
        __syncthreads();   // A: prev chunk's readers done

        // ---- cvt + store K (row-major) and V (transposed, bank-spread) ----
        {
            short4 k4 = { f2bf(pK.x), f2bf(pK.y), f2bf(pK.z), f2bf(pK.w) };
            *(short4*)&Ks[r_st * KSTR + 4 * c16] = k4;
            const int d0 = 4 * c16;
            Vt[(d0 + 0) * VSTR + r_st] = f2bf(pV.x);
            Vt[(d0 + 1) * VSTR + r_st] = f2bf(pV.y);
            Vt[(d0 + 2) * VSTR + r_st] = f2bf(pV.z);
            Vt[(d0 + 3) * VSTR + r_st] = f2bf(pV.w);
        }
        __syncthreads();   // B: tiles visible

        // ---- prefetch next chunk (lands during compute) ----
        if (c < 4) {
            const int kb = q0 - 256 + 64 * (c + 1);
            const size_t base = (size_t)(b * 4096 + kb + r_st) * 48;
            pK = qkv4[base + 16 + c16];
            pV = qkv4[base + 32 + c16];
        }

        // ---- S = Q K^T over this group's single 16-key tile ----
        f32x4 sc = (f32x4){0.f, 0.f, 0.f, 0.f};
        {
            const frag kf0 = *(const frag*)&Ks[(16 * g + cl) * KSTR + 8 * quad];
            const frag kf1 = *(const frag*)&Ks[(16 * g + cl) * KSTR + 32 + 8 * quad];
            sc = __builtin_amdgcn_mfma_f32_16x16x32_bf16(qf0, kf0, sc, 0, 0, 0);
            sc = __builtin_amdgcn_mfma_f32_16x16x32_bf16(qf1, kf1, sc, 0, 0, 0);
        }

        // ---- sliding-window mask (edge chunks only) ----
        if (c == 4) {           // causal: keep key <= query
            #pragma unroll
            for (int r = 0; r < 4; ++r)
                if (16 * s + ql + r < 16 * g + cl) sc[r] = -1e30f;
        } else if (c == 0) {    // left edge (only runs when q0 >= 256)
            #pragma unroll
            for (int r = 0; r < 4; ++r)
                if (16 * s + ql + r > 16 * g + cl) sc[r] = -1e30f;
        }

        // ---- online softmax (DPP 16-lane reductions) ----
        #pragma unroll
        for (int r = 0; r < 4; ++r) {
            const float mx = red16_max(sc[r]);
            const float mnew  = fmaxf(m[r], mx);
            const float alpha = __builtin_amdgcn_exp2f((m[r] - mnew) * LOG2E);
            m[r] = mnew;
            // guard: fully-masked tile would give exp(-1e30 - -1e30)=1
            const float p = (sc[r] <= -1e29f)
                              ? 0.f
                              : __builtin_amdgcn_exp2f((sc[r] - mnew) * LOG2E);
            Pw[w][(ql + r) * PSTR + cl] = f2bf(p);
            l[r] = l[r] * alpha + red16_sum(p);
            #pragma unroll
            for (int n4 = 0; n4 < 4; ++n4) oacc[n4][r] *= alpha;
        }

        // ---- O += P V  (P wave-private: lgkmcnt only, no barrier).
        // K=32 MFMA; k-slots 16..31 (quads 2-3) are register zeros. ----
        frag pf = (frag){0, 0, 0, 0, 0, 0, 0, 0};
        if (quad < 2) pf = *(const frag*)&Pw[w][cl * PSTR + 8 * quad];
        #pragma unroll
        for (int n4 = 0; n4 < 4; ++n4) {
            frag vf = (frag){0, 0, 0, 0, 0, 0, 0, 0};
            if (quad < 2)
                vf = *(const frag*)&Vt[(16 * n4 + cl) * VSTR + 16 * g + 8 * quad];
            oacc[n4] = __builtin_amdgcn_mfma_f32_16x16x32_bf16(pf, vf, oacc[n4], 0, 0, 0);
        }
    }

    // ---- merge the four key-groups per stripe (round-5-verified form) ----
    if (g != 0) {
        #pragma unroll
        for (int n4 = 0; n4 < 4; ++n4)
            #pragma unroll
            for (int r = 0; r < 4; ++r)
                Om[s][g - 1][(ql + r) * OSTR + 16 * n4 + cl] = oacc[n4][r];
        if (cl == 0)
            #pragma unroll
            for (int r = 0; r < 4; ++r)
                mlbuf[s][g - 1][ql + r] = make_float2(m[r], l[r]);
    }
    __syncthreads();
    if (g == 0) {
        #pragma unroll
        for (int r = 0; r < 4; ++r) {
            float M = m[r];
            float L = l[r];
            float acc[4];
            #pragma unroll
            for (int n4 = 0; n4 < 4; ++n4) acc[n4] = oacc[n4][r];
            #pragma unroll
            for (int p = 0; p < 3; ++p) {
                const float2 ml = mlbuf[s][p][ql + r];
                const float Mn = fmaxf(M, ml.x);
                const float a0 = __builtin_amdgcn_exp2f((M    - Mn) * LOG2E);
                const float a1 = __builtin_amdgcn_exp2f((ml.x - Mn) * LOG2E);
                L = L * a0 + ml.y * a1;
                #pragma unroll
                for (int n4 = 0; n4 < 4; ++n4)
                    acc[n4] = acc[n4] * a0
                            + Om[s][p][(ql + r) * OSTR + 16 * n4 + cl] * a1;
                M = Mn;
            }
            const float inv = 1.0f / L;
            const size_t row = (size_t)(b * 4096 + q0 + 16 * s + ql + r) * 64;
            #pragma unroll
            for (int n4 = 0; n4 < 4; ++n4)
                out[row + 16 * n4 + cl] = acc[n4] * inv;
        }
    }
}

extern "C" void kernel_launch(void* const* d_in, const int* in_sizes, int n_in,
                              void* d_out, int out_size, void* d_ws, size_t ws_size,
                              hipStream_t stream) {
    const float* qkv = (const float*)d_in[0];
    float* out = (float*)d_out;
    dim3 grid(64, 4);
    dim3 block(1024);
    hipLaunchKernelGGL(swa_mfma6, grid, block, 0, stream, qkv, out);
}

// Round 4
// 69.987 us; speedup vs baseline: 1.0600x; 1.0117x over previous
//
#include <hip/hip_runtime.h>
#include <hip/hip_bf16.h>

// Sliding-window causal attention, B=4, S=4096, d=64, window [i-256, i].
// Round 7: r3 (67.3 µs best) + LDS double-buffer for K/V — the ONLY change.
//  - Staging (cvt + ds_write) for chunk c+1 issues BEFORE compute of chunk c,
//    into the idle buffer, and completes underneath the MFMA/softmax work.
//  - Barrier A (readers-done-before-overwrite) is gone: writes target the
//    other buffer. One barrier per chunk; 11 -> 7 total.
//  - Global prefetch moved 2 chunks ahead (issued during compute of c for
//    c+2): a full compute phase covers the load latency.
//  - Compute, wave decomposition (4 stripes x 2 key-groups), softmax, merge:
//    bit-identical to r3.
// LDS 73.5 KB, 8 waves, grid 256 = 1 block/CU (grid-limited).
// Layouts (HW-verified per guide §3): A[m=lane&15][k=quad*8+j];
// C/D col=lane&15, row=quad*4+reg.

#define LOG2E 1.4426950408889634f

typedef __attribute__((ext_vector_type(8))) short  frag;    // 8 bf16
typedef __attribute__((ext_vector_type(4))) float  f32x4;   // C/D

static __device__ inline short f2bf(float x) {
    __hip_bfloat16 h = __float2bfloat16(x);   // RTNE
    return __builtin_bit_cast(short, h);
}

#define DPPF(x, ctrl) __builtin_bit_cast(float, \
    __builtin_amdgcn_mov_dpp(__builtin_bit_cast(int, (x)), (ctrl), 0xF, 0xF, true))

static __device__ inline float red16_max(float x) {
    x = fmaxf(x, DPPF(x, 0xB1));   // quad_perm xor 1
    x = fmaxf(x, DPPF(x, 0x4E));   // quad_perm xor 2
    x = fmaxf(x, DPPF(x, 0x141));  // row_half_mirror (~xor 4)
    x = fmaxf(x, DPPF(x, 0x140));  // row_mirror      (~xor 8)
    return x;
}
static __device__ inline float red16_sum(float x) {
    x += DPPF(x, 0xB1);
    x += DPPF(x, 0x4E);
    x += DPPF(x, 0x141);
    x += DPPF(x, 0x140);
    return x;
}

#define LSTR 72   // K/V/Q LDS row stride (bf16)
#define PSTR 40   // P tile row stride (16 x 32 keys + pad)
#define OSTR 65   // merge buffer row stride (fp32)

__global__ __launch_bounds__(512, 2) void swa_mfma7(const float* __restrict__ qkv,
                                                    float* __restrict__ out)
{
    __shared__ short Qs[64 * LSTR];          //  9216 B
    __shared__ short Ks[2][64 * LSTR];       // 18432 B  double-buffered
    __shared__ short Vt[2][64 * LSTR];       // 18432 B  Vt[dim][key], dbuf
    __shared__ short Pw[8][16 * PSTR];       // 10240 B  per-wave P
    __shared__ float Om[4][16 * OSTR];       // 16640 B  group-1 O partials
    __shared__ float2 mlbuf[4][16];          //   512 B
    // total 73.5 KB

    const int b    = blockIdx.y;
    const int q0   = blockIdx.x * 64;
    const int t    = threadIdx.x;
    const int w    = t >> 6;        // 0..7
    const int s    = w & 3;         // query stripe: rows 16s..16s+15
    const int g    = w >> 2;        // key group: tiles {2g, 2g+1}
    const int lane = t & 63;
    const int cl   = lane & 15;
    const int quad = lane >> 4;
    const int ql   = 4 * quad;

    const float4* qkv4 = (const float4*)qkv;   // 48 float4 per (b,seq) row
    const int r_st = t >> 3;        // staging row 0..63
    const int c8   = t & 7;         // staging float4-col (two: c8, c8+8)

    const int c0 = (q0 >= 256) ? 0 : (4 - (q0 >> 6));

    // ---- stage Q (x 1/8 scale folded in) ----
    {
        const size_t base = (size_t)(b * 4096 + q0 + r_st) * 48;
        #pragma unroll
        for (int i = 0; i < 2; ++i) {
            float4 v = qkv4[base + c8 + 8 * i];
            short4 s4 = { f2bf(v.x * 0.125f), f2bf(v.y * 0.125f),
                          f2bf(v.z * 0.125f), f2bf(v.w * 0.125f) };
            *(short4*)&Qs[r_st * LSTR + 4 * (c8 + 8 * i)] = s4;
        }
    }

    float4 preK[2], preV[2];
    auto fetch = [&](int c) {
        const int kb = q0 - 256 + 64 * c;
        const size_t base = (size_t)(b * 4096 + kb + r_st) * 48;
        #pragma unroll
        for (int i = 0; i < 2; ++i) {
            preK[i] = qkv4[base + 16 + c8 + 8 * i];
            preV[i] = qkv4[base + 32 + c8 + 8 * i];
        }
    };
    auto stage = [&](int p) {   // cvt + store K (row-major) and V (transposed)
        #pragma unroll
        for (int i = 0; i < 2; ++i) {
            short4 k4 = { f2bf(preK[i].x), f2bf(preK[i].y),
                          f2bf(preK[i].z), f2bf(preK[i].w) };
            *(short4*)&Ks[p][r_st * LSTR + 4 * (c8 + 8 * i)] = k4;
            const int d0 = 4 * (c8 + 8 * i);
            Vt[p][(d0 + 0) * LSTR + r_st] = f2bf(preV[i].x);
            Vt[p][(d0 + 1) * LSTR + r_st] = f2bf(preV[i].y);
            Vt[p][(d0 + 2) * LSTR + r_st] = f2bf(preV[i].z);
            Vt[p][(d0 + 3) * LSTR + r_st] = f2bf(preV[i].w);
        }
    };

    // ---- prologue: chunk c0 into buf 0; prefetch c0+1 ----
    fetch(c0);
    stage(0);
    if (c0 < 4) fetch(c0 + 1);

    __syncthreads();   // Qs + buf0 visible
    const frag qf0 = *(const frag*)&Qs[(16 * s + cl) * LSTR + 8 * quad];
    const frag qf1 = *(const frag*)&Qs[(16 * s + cl) * LSTR + 32 + 8 * quad];

    float m[4], l[4];
    f32x4 oacc[4];
    #pragma unroll
    for (int r = 0; r < 4; ++r) { m[r] = -1e30f; l[r] = 0.f; }
    #pragma unroll
    for (int n4 = 0; n4 < 4; ++n4) oacc[n4] = (f32x4){0.f, 0.f, 0.f, 0.f};

    for (int c = c0; c < 5; ++c) {
        const int p = (c - c0) & 1;

        // ---- stage next chunk into the idle buffer (hides under compute) ----
        if (c < 4) stage(p ^ 1);
        // ---- prefetch chunk c+2 (a full compute phase of latency cover) ----
        if (c < 3) fetch(c + 2);

        // ---- S = Q K^T over this group's 2 key-tiles ----
        f32x4 sc[2];
        #pragma unroll
        for (int u = 0; u < 2; ++u) {
            const int t4 = 2 * g + u;
            sc[u] = (f32x4){0.f, 0.f, 0.f, 0.f};
            const frag kf0 = *(const frag*)&Ks[p][(16 * t4 + cl) * LSTR + 8 * quad];
            const frag kf1 = *(const frag*)&Ks[p][(16 * t4 + cl) * LSTR + 32 + 8 * quad];
            sc[u] = __builtin_amdgcn_mfma_f32_16x16x32_bf16(qf0, kf0, sc[u], 0, 0, 0);
            sc[u] = __builtin_amdgcn_mfma_f32_16x16x32_bf16(qf1, kf1, sc[u], 0, 0, 0);
        }

        // ---- sliding-window mask (edge chunks only) ----
        if (c == 4) {           // causal: keep key <= query
            #pragma unroll
            for (int u = 0; u < 2; ++u) {
                const int t4 = 2 * g + u;
                #pragma unroll
                for (int r = 0; r < 4; ++r)
                    if (16 * s + ql + r < 16 * t4 + cl) sc[u][r] = -1e30f;
            }
        } else if (c == 0) {    // left edge: keep key >= query
            #pragma unroll
            for (int u = 0; u < 2; ++u) {
                const int t4 = 2 * g + u;
                #pragma unroll
                for (int r = 0; r < 4; ++r)
                    if (16 * s + ql + r > 16 * t4 + cl) sc[u][r] = -1e30f;
            }
        }

        // ---- online softmax (DPP 16-lane reductions) ----
        #pragma unroll
        for (int r = 0; r < 4; ++r) {
            float mx = red16_max(fmaxf(sc[0][r], sc[1][r]));
            const float mnew  = fmaxf(m[r], mx);
            const float alpha = __builtin_amdgcn_exp2f((m[r] - mnew) * LOG2E);
            m[r] = mnew;
            float sum = 0.f;
            #pragma unroll
            for (int u = 0; u < 2; ++u) {
                // guard: fully-masked tile would give exp(-1e30 - -1e30)=1
                float pv = (sc[u][r] <= -1e29f)
                            ? 0.f
                            : __builtin_amdgcn_exp2f((sc[u][r] - mnew) * LOG2E);
                Pw[w][(ql + r) * PSTR + 16 * u + cl] = f2bf(pv);
                sum += pv;
            }
            l[r] = l[r] * alpha + red16_sum(sum);
            #pragma unroll
            for (int n4 = 0; n4 < 4; ++n4) oacc[n4][r] *= alpha;
        }

        // ---- O += P V  (P wave-private: lgkmcnt only, no barrier) ----
        const frag pf = *(const frag*)&Pw[w][cl * PSTR + 8 * quad];
        #pragma unroll
        for (int n4 = 0; n4 < 4; ++n4) {
            const frag vf = *(const frag*)&Vt[p][(16 * n4 + cl) * LSTR + 32 * g + 8 * quad];
            oacc[n4] = __builtin_amdgcn_mfma_f32_16x16x32_bf16(pf, vf, oacc[n4], 0, 0, 0);
        }

        __syncthreads();   // next chunk's staged tiles visible; readers done
    }

    // ---- merge the two key-groups per stripe ----
    if (g == 1) {
        #pragma unroll
        for (int n4 = 0; n4 < 4; ++n4)
            #pragma unroll
            for (int r = 0; r < 4; ++r)
                Om[s][(ql + r) * OSTR + 16 * n4 + cl] = oacc[n4][r];
        if (cl == 0)
            #pragma unroll
            for (int r = 0; r < 4; ++r)
                mlbuf[s][ql + r] = make_float2(m[r], l[r]);
    }
    __syncthreads();
    if (g == 0) {
        #pragma unroll
        for (int r = 0; r < 4; ++r) {
            const float2 ml1 = mlbuf[s][ql + r];
            const float M  = fmaxf(m[r], ml1.x);
            const float a0 = __builtin_amdgcn_exp2f((m[r]  - M) * LOG2E);
            const float a1 = __builtin_amdgcn_exp2f((ml1.x - M) * LOG2E);
            const float L  = l[r] * a0 + ml1.y * a1;
            const float inv = 1.0f / L;
            const size_t row = (size_t)(b * 4096 + q0 + 16 * s + ql + r) * 64;
            #pragma unroll
            for (int n4 = 0; n4 < 4; ++n4) {
                const float o1 = Om[s][(ql + r) * OSTR + 16 * n4 + cl];
                out[row + 16 * n4 + cl] = (oacc[n4][r] * a0 + o1 * a1) * inv;
            }
        }
    }
}

extern "C" void kernel_launch(void* const* d_in, const int* in_sizes, int n_in,
                              void* d_out, int out_size, void* d_ws, size_t ws_size,
                              hipStream_t stream) {
    const float* qkv = (const float*)d_in[0];
    float* out = (float*)d_out;
    dim3 grid(64, 4);
    dim3 block(512);
    hipLaunchKernelGGL(swa_mfma7, grid, block, 0, stream, qkv, out);
}

// Round 5
// 67.818 us; speedup vs baseline: 1.0939x; 1.0320x over previous
//
#include <hip/hip_runtime.h>
#include <hip/hip_bf16.h>

// Sliding-window causal attention, B=4, S=4096, d=64, window [i-256, i].
// Round 8: EXACT r3 structure (67.3 µs best) with ONLY the LDS strides changed.
// Theory: LSTR=72 (36 words == 4 mod 32) made every hot ds_read_b128 an 8-way
// bank conflict: bank = 4*(cl+quad) mod 32 for Q/K/V reads, (5cl+quad) mod 8
// for the P read -> ~2.9x DS cost on 9 b128 reads/wave/chunk (~5-6 us/CU).
// This throughput serialization is invariant under all the structural changes
// tried in r4-r7, which is why none of them helped.
// Fix: LSTR 70 (35 words == 3 mod 32): reads ~2-way (free, m136); V b16
// transpose-stores land on 32 distinct banks (12*c8 + r/2 spread). PSTR 42
// (21 words): P-fragment read ~2-way. Zero logic changes.
// Layouts (HW-verified per guide §3): A[m=lane&15][k=quad*8+j];
// C/D col=lane&15, row=quad*4+reg.

#define LOG2E 1.4426950408889634f

typedef __attribute__((ext_vector_type(8))) short  frag;    // 8 bf16
typedef __attribute__((ext_vector_type(4))) float  f32x4;   // C/D

static __device__ inline short f2bf(float x) {
    __hip_bfloat16 h = __float2bfloat16(x);   // RTNE
    return __builtin_bit_cast(short, h);
}

// DPP cross-lane within a 16-lane row: xor1, xor2, then half-mirror (==xor4
// once quad-uniform) and mirror (==xor8 once 8-uniform).
#define DPPF(x, ctrl) __builtin_bit_cast(float, \
    __builtin_amdgcn_mov_dpp(__builtin_bit_cast(int, (x)), (ctrl), 0xF, 0xF, true))

static __device__ inline float red16_max(float x) {
    x = fmaxf(x, DPPF(x, 0xB1));   // quad_perm [1,0,3,2]  (xor 1)
    x = fmaxf(x, DPPF(x, 0x4E));   // quad_perm [2,3,0,1]  (xor 2)
    x = fmaxf(x, DPPF(x, 0x141));  // row_half_mirror      (xor 7 ~ xor 4)
    x = fmaxf(x, DPPF(x, 0x140));  // row_mirror           (xor 15 ~ xor 8)
    return x;
}
static __device__ inline float red16_sum(float x) {
    x += DPPF(x, 0xB1);
    x += DPPF(x, 0x4E);
    x += DPPF(x, 0x141);
    x += DPPF(x, 0x140);
    return x;
}

#define LSTR 70   // K/V/Q LDS row stride (bf16): 35 words == 3 (mod 32)
#define PSTR 42   // P tile row stride: 21 words == 21 (mod 32), ~2-way
#define OSTR 65   // merge buffer row stride (fp32); epilogue-only, once

__global__ __launch_bounds__(512, 2) void swa_mfma8(const float* __restrict__ qkv,
                                                    float* __restrict__ out)
{
    __shared__ short Qs[64 * LSTR];
    __shared__ short Ks[64 * LSTR];
    __shared__ short Vt[64 * LSTR];       // Vt[dim][key]
    __shared__ short Pw[8][16 * PSTR];    // per-wave P (16 q x 32 keys)
    __shared__ float Om[4][16 * OSTR];    // group-1 O partials per stripe
    __shared__ float2 mlbuf[4][16];       // group-1 (m,l) per stripe row

    const int b    = blockIdx.y;
    const int q0   = blockIdx.x * 64;
    const int t    = threadIdx.x;
    const int w    = t >> 6;        // 0..7
    const int s    = w & 3;         // query stripe: rows 16s..16s+15
    const int g    = w >> 2;        // key group: tiles {2g, 2g+1}
    const int lane = t & 63;
    const int cl   = lane & 15;
    const int quad = lane >> 4;
    const int ql   = 4 * quad;

    const float4* qkv4 = (const float4*)qkv;   // 48 float4 per (b,seq) row
    const int r_st = t >> 3;        // staging row 0..63
    const int c8   = t & 7;         // staging float4-col (two: c8, c8+8)

    // ---- stage Q (x 1/8 exact) ----
    {
        const size_t base = (size_t)(b * 4096 + q0 + r_st) * 48;
        #pragma unroll
        for (int i = 0; i < 2; ++i) {
            float4 v = qkv4[base + c8 + 8 * i];
            short4 s4 = { f2bf(v.x * 0.125f), f2bf(v.y * 0.125f),
                          f2bf(v.z * 0.125f), f2bf(v.w * 0.125f) };
            *(short4*)&Qs[r_st * LSTR + 4 * (c8 + 8 * i)] = s4;
        }
    }

    const int c0 = (q0 >= 256) ? 0 : (4 - (q0 >> 6));

    // ---- prefetch chunk c0 ----
    float4 preK[2], preV[2];
    {
        const int kb = q0 - 256 + 64 * c0;
        const size_t base = (size_t)(b * 4096 + kb + r_st) * 48;
        #pragma unroll
        for (int i = 0; i < 2; ++i) {
            preK[i] = qkv4[base + 16 + c8 + 8 * i];
            preV[i] = qkv4[base + 32 + c8 + 8 * i];
        }
    }

    __syncthreads();   // Qs visible
    const frag qf0 = *(const frag*)&Qs[(16 * s + cl) * LSTR + 8 * quad];
    const frag qf1 = *(const frag*)&Qs[(16 * s + cl) * LSTR + 32 + 8 * quad];

    float m[4], l[4];
    f32x4 oacc[4];
    #pragma unroll
    for (int r = 0; r < 4; ++r) { m[r] = -1e30f; l[r] = 0.f; }
    #pragma unroll
    for (int n4 = 0; n4 < 4; ++n4) oacc[n4] = (f32x4){0.f, 0.f, 0.f, 0.f};

    for (int c = c0; c < 5; ++c) {
        __syncthreads();   // A: prev chunk's readers done

        // ---- cvt + store K (row-major) and V (transposed) ----
        #pragma unroll
        for (int i = 0; i < 2; ++i) {
            short4 k4 = { f2bf(preK[i].x), f2bf(preK[i].y),
                          f2bf(preK[i].z), f2bf(preK[i].w) };
            *(short4*)&Ks[r_st * LSTR + 4 * (c8 + 8 * i)] = k4;
            const int d0 = 4 * (c8 + 8 * i);
            Vt[(d0 + 0) * LSTR + r_st] = f2bf(preV[i].x);
            Vt[(d0 + 1) * LSTR + r_st] = f2bf(preV[i].y);
            Vt[(d0 + 2) * LSTR + r_st] = f2bf(preV[i].z);
            Vt[(d0 + 3) * LSTR + r_st] = f2bf(preV[i].w);
        }
        __syncthreads();   // B: tiles visible

        // ---- prefetch next chunk (lands during compute) ----
        if (c < 4) {
            const int kb = q0 - 256 + 64 * (c + 1);
            const size_t base = (size_t)(b * 4096 + kb + r_st) * 48;
            #pragma unroll
            for (int i = 0; i < 2; ++i) {
                preK[i] = qkv4[base + 16 + c8 + 8 * i];
                preV[i] = qkv4[base + 32 + c8 + 8 * i];
            }
        }

        // ---- S = Q K^T over this group's 2 key-tiles ----
        f32x4 sc[2];
        #pragma unroll
        for (int u = 0; u < 2; ++u) {
            const int t4 = 2 * g + u;
            sc[u] = (f32x4){0.f, 0.f, 0.f, 0.f};
            const frag kf0 = *(const frag*)&Ks[(16 * t4 + cl) * LSTR + 8 * quad];
            const frag kf1 = *(const frag*)&Ks[(16 * t4 + cl) * LSTR + 32 + 8 * quad];
            sc[u] = __builtin_amdgcn_mfma_f32_16x16x32_bf16(qf0, kf0, sc[u], 0, 0, 0);
            sc[u] = __builtin_amdgcn_mfma_f32_16x16x32_bf16(qf1, kf1, sc[u], 0, 0, 0);
        }

        // ---- sliding-window mask (edge chunks only) ----
        if (c == 4) {           // causal: keep key <= query
            #pragma unroll
            for (int u = 0; u < 2; ++u) {
                const int t4 = 2 * g + u;
                #pragma unroll
                for (int r = 0; r < 4; ++r)
                    if (16 * s + ql + r < 16 * t4 + cl) sc[u][r] = -1e30f;
            }
        } else if (c == 0) {    // left edge: keep key >= query
            #pragma unroll
            for (int u = 0; u < 2; ++u) {
                const int t4 = 2 * g + u;
                #pragma unroll
                for (int r = 0; r < 4; ++r)
                    if (16 * s + ql + r > 16 * t4 + cl) sc[u][r] = -1e30f;
            }
        }

        // ---- online softmax (DPP 16-lane reductions) ----
        #pragma unroll
        for (int r = 0; r < 4; ++r) {
            float mx = red16_max(fmaxf(sc[0][r], sc[1][r]));
            const float mnew  = fmaxf(m[r], mx);
            const float alpha = __builtin_amdgcn_exp2f((m[r] - mnew) * LOG2E);
            m[r] = mnew;
            float sum = 0.f;
            #pragma unroll
            for (int u = 0; u < 2; ++u) {
                // guard: fully-masked tile would give exp(-1e30 - -1e30)=1
                float p = (sc[u][r] <= -1e29f)
                            ? 0.f
                            : __builtin_amdgcn_exp2f((sc[u][r] - mnew) * LOG2E);
                Pw[w][(ql + r) * PSTR + 16 * u + cl] = f2bf(p);
                sum += p;
            }
            l[r] = l[r] * alpha + red16_sum(sum);
            #pragma unroll
            for (int n4 = 0; n4 < 4; ++n4) oacc[n4][r] *= alpha;
        }

        // ---- O += P V  (P wave-private: lgkmcnt only, no barrier) ----
        const frag pf = *(const frag*)&Pw[w][cl * PSTR + 8 * quad];
        #pragma unroll
        for (int n4 = 0; n4 < 4; ++n4) {
            const frag vf = *(const frag*)&Vt[(16 * n4 + cl) * LSTR + 32 * g + 8 * quad];
            oacc[n4] = __builtin_amdgcn_mfma_f32_16x16x32_bf16(pf, vf, oacc[n4], 0, 0, 0);
        }
    }

    // ---- merge the two key-groups per stripe ----
    if (g == 1) {
        #pragma unroll
        for (int n4 = 0; n4 < 4; ++n4)
            #pragma unroll
            for (int r = 0; r < 4; ++r)
                Om[s][(ql + r) * OSTR + 16 * n4 + cl] = oacc[n4][r];
        if (cl == 0)
            #pragma unroll
            for (int r = 0; r < 4; ++r)
                mlbuf[s][ql + r] = make_float2(m[r], l[r]);
    }
    __syncthreads();
    if (g == 0) {
        #pragma unroll
        for (int r = 0; r < 4; ++r) {
            const float2 ml1 = mlbuf[s][ql + r];
            const float M  = fmaxf(m[r], ml1.x);
            const float a0 = __builtin_amdgcn_exp2f((m[r]  - M) * LOG2E);
            const float a1 = __builtin_amdgcn_exp2f((ml1.x - M) * LOG2E);
            const float L  = l[r] * a0 + ml1.y * a1;
            const float inv = 1.0f / L;
            const size_t row = (size_t)(b * 4096 + q0 + 16 * s + ql + r) * 64;
            #pragma unroll
            for (int n4 = 0; n4 < 4; ++n4) {
                const float o1 = Om[s][(ql + r) * OSTR + 16 * n4 + cl];
                out[row + 16 * n4 + cl] = (oacc[n4][r] * a0 + o1 * a1) * inv;
            }
        }
    }
}

extern "C" void kernel_launch(void* const* d_in, const int* in_sizes, int n_in,
                              void* d_out, int out_size, void* d_ws, size_t ws_size,
                              hipStream_t stream) {
    const float* qkv = (const float*)d_in[0];
    float* out = (float*)d_out;
    dim3 grid(64, 4);
    dim3 block(512);
    hipLaunchKernelGGL(swa_mfma8, grid, block, 0, stream, qkv, out);
}